// Round 7
// baseline (87.145 us; speedup 1.0000x reference)
//
#include <hip/hip_runtime.h>

// NBCModel: non-backtracking closed-walk signature + MLP.
// B[i,j] = (dst_j == src_i) && (src_j != dst_i).  sig[g,k] = sum over edges i
// in graph g of diag(B^{k+1})_i.  out[g] = relu(sig @ W1 + b1) @ W2 + b2.
//
// R1 DFS 151; R2 BFS 90.5; R3 ballot neutral; R4 16-wave 81.4; R5 3-kernel
// split 82.1; R6 single-kernel chain-build 73.75. Persistent ~4-6x gap vs
// bottom-up estimate points at single-CU serial-phase latency. R7: 32 blocks,
// each redundantly builds the chain adjacency in its own LDS (~1us) and BFS's
// a 64-start slice -> 32-way parallelism for every phase, still ONE graph
// node. Sig accumulates in d_ws on top of the 0xAA poison (subtracted at
// read); last-arriving block (poison-based arrival counter) runs the MLP.

typedef unsigned long long u64;
typedef unsigned int u32;

constexpr int E_EDGES = 2048;
constexpr int L_WALK  = 8;
constexpr int G_GRAPHS = 128;
constexpr int HID     = 128;
constexpr int N_NODES = 4096;
constexpr int NB      = 32;               // blocks
constexpr int TPB     = 256;              // threads per block
constexpr int SLICE   = E_EDGES / NB;     // 64 start edges per block
constexpr int CAP     = 1024;             // per-slice frontier cap (~5x headroom, R5-proven)
constexpr u32 POISON  = 0xAAAAAAAAu;      // harness d_ws poison pattern

__launch_bounds__(TPB, 1)
__global__ void nbc_fused(const int* __restrict__ edge_index,
                          const int* __restrict__ edge_graph,
                          const float* __restrict__ W1,
                          const float* __restrict__ b1,
                          const float* __restrict__ W2,
                          const float* __restrict__ b2,
                          u32* __restrict__ gsig,   // d_ws+0: 1024 u32, poison-based
                          u32* __restrict__ ctr,    // d_ws+4096: arrival counter
                          float* __restrict__ out)
{
    // node entry q: src(0:12) | dst(12:24) | hs=head[src](24:36) | next(36:48)
    // frontier  e: s(0:11) | dst_cur(11:23) | ptr(23:35) | g(35:42)
    __shared__ int s_head[N_NODES];        // 16 KB
    __shared__ u64 s_node[E_EDGES];        // 16 KB
    __shared__ u64 bufA[CAP];              // 8 KB
    __shared__ u64 bufB[CAP];              // 8 KB
    __shared__ int s_sig[G_GRAPHS * L_WALK]; // 4 KB
    __shared__ int s_nn[L_WALK + 1];
    __shared__ int s_last;

    const int t    = threadIdx.x;
    const int lane = t & 63;
    const int blk  = blockIdx.x;

    // ---- load owned edges (8/thread, int4-vectorized, coalesced) ----
    const int4* s4 = (const int4*)(edge_index);
    const int4* d4 = (const int4*)(edge_index + E_EDGES);
    const int4* g4 = (const int4*)(edge_graph);
    int sev[8], dev[8], gev[8], prevv[8];
    *(int4*)&sev[0] = s4[2 * t]; *(int4*)&sev[4] = s4[2 * t + 1];
    *(int4*)&dev[0] = d4[2 * t]; *(int4*)&dev[4] = d4[2 * t + 1];
    *(int4*)&gev[0] = g4[2 * t]; *(int4*)&gev[4] = g4[2 * t + 1];

    #pragma unroll
    for (int i = 0; i < 16; ++i) s_head[t + TPB * i] = -1;
    #pragma unroll
    for (int i = 0; i < 4; ++i) s_sig[t + TPB * i] = 0;
    if (t <= L_WALK) s_nn[t] = (t == 0) ? SLICE : 0;
    __syncthreads();

    // ---- chain build: head[x] = list of edges b with dst_b == x ----
    #pragma unroll
    for (int i = 0; i < 8; ++i)
        prevv[i] = atomicExch(&s_head[dev[i]], t * 8 + i);
    __syncthreads();

    // ---- embed hs = head[src_e]; single node write; level-0 for our slice ----
    #pragma unroll
    for (int i = 0; i < 8; ++i) {
        const int e  = t * 8 + i;
        const int hs = s_head[sev[i]] & 0xFFF;
        s_node[e] = (u64)sev[i]
                  | ((u64)dev[i] << 12)
                  | ((u64)hs << 24)
                  | ((u64)(prevv[i] & 0xFFF) << 36);
        const int rel = e - blk * SLICE;
        if ((unsigned)rel < (unsigned)SLICE)
            bufA[rel] = (u64)e | ((u64)dev[i] << 11) | ((u64)hs << 23)
                      | ((u64)gev[i] << 35);
    }
    __syncthreads();

    // ---- BFS levels 0..7 over our 64-start slice ----
    u64* cur = bufA;
    u64* nxt = bufB;
    for (int d = 0; d < L_WALK; ++d) {
        int n_cur = s_nn[d];
        if (n_cur > CAP) n_cur = CAP;
        for (int idx = t; idx < n_cur; idx += TPB) {
            u64 e = cur[idx];
            int s   = (int)( e        & 0x7FF);
            int dcc = (int)((e >> 11) & 0xFFF);
            int ptr = (int)((e >> 23) & 0xFFF);
            u64 gb  = e & (0x7Full << 35);
            while (ptr != 0xFFF) {
                u64 q = s_node[ptr];
                int sb = (int)(q & 0xFFF);
                int nx = (int)((q >> 36) & 0xFFF);
                if (sb != dcc) {                         // non-backtracking
                    if (ptr == s)
                        atomicAdd(&s_sig[(int)(gb >> 35) * L_WALK + d], 1);
                    if (d < L_WALK - 1) {
                        u64 e2 = (u64)s | (((q >> 12) & 0xFFFFFFull) << 11) | gb;
                        u64 m = __ballot(1);
                        int leader = __ffsll(m) - 1;
                        int rank   = __popcll(m & ((1ull << lane) - 1ull));
                        int bpos = 0;
                        if (lane == leader) bpos = atomicAdd(&s_nn[d + 1], (int)__popcll(m));
                        bpos = __shfl(bpos, leader);
                        if (bpos + rank < CAP) nxt[bpos + rank] = e2;
                    }
                }
                ptr = nx;
            }
        }
        u64* tmp = cur; cur = nxt; nxt = tmp;
        __syncthreads();
    }

    // ---- publish slice counts: atomicAdd on top of the 0xAA poison ----
    #pragma unroll
    for (int i = 0; i < 4; ++i) {
        int v = s_sig[t + TPB * i];
        if (v) atomicAdd(&gsig[t + TPB * i], (u32)v);
    }
    __syncthreads();                       // drains all this block's global atomics

    // ---- arrival: 32nd block performs the epilogue ----
    if (t == 0) {
        __threadfence();
        u32 old = atomicAdd(ctr, 1u);
        s_last = (old == POISON + (u32)(NB - 1)) ? 1 : 0;
    }
    __syncthreads();
    if (!s_last) return;

    // ---- last block: coherent sig gather, then MLP ----
    #pragma unroll
    for (int i = 0; i < 4; ++i) {
        int idx = t + TPB * i;
        u32 v = atomicAdd(&gsig[idx], 0u);  // device-coherent read
        s_sig[idx] = (int)(v - POISON);
    }
    __syncthreads();

    float* s_part = (float*)bufA;          // frontier dead; reuse
    {
        const int g   = t >> 1;
        const int sub = t & 1;
        float sv[L_WALK];
        #pragma unroll
        for (int k = 0; k < L_WALK; ++k) sv[k] = (float)s_sig[g * L_WALK + k];
        float o = 0.0f;
        const int j0 = sub * 64;
        for (int jj = 0; jj < 64; ++jj) {
            int j = j0 + jj;
            float a = b1[j];
            #pragma unroll
            for (int k = 0; k < L_WALK; ++k) a += sv[k] * W1[k * HID + j];
            o += fmaxf(a, 0.0f) * W2[j];
        }
        s_part[t] = o;
    }
    __syncthreads();
    if (t < G_GRAPHS)
        out[t] = b2[0] + s_part[2 * t] + s_part[2 * t + 1];
}

extern "C" void kernel_launch(void* const* d_in, const int* in_sizes, int n_in,
                              void* d_out, int out_size, void* d_ws, size_t ws_size,
                              hipStream_t stream) {
    const int*   edge_index = (const int*)d_in[0];
    const int*   edge_graph = (const int*)d_in[1];
    const float* W1 = (const float*)d_in[2];
    const float* b1 = (const float*)d_in[3];
    const float* W2 = (const float*)d_in[4];
    const float* b2 = (const float*)d_in[5];
    float* out = (float*)d_out;

    u32* gsig = (u32*)d_ws;              // 1024 u32 (poison-based accumulators)
    u32* ctr  = gsig + 1024;             // arrival counter (poison-based)

    nbc_fused<<<NB, TPB, 0, stream>>>(edge_index, edge_graph, W1, b1, W2, b2,
                                      gsig, ctr, out);
}

// Round 8
// 76.478 us; speedup vs baseline: 1.1395x; 1.1395x over previous
//
#include <hip/hip_runtime.h>

// NBCModel: non-backtracking closed-walk signature + MLP.
// B[i,j] = (dst_j == src_i) && (src_j != dst_i).  sig[g,k] = sum over edges i
// in graph g of diag(B^{k+1})_i.  out[g] = relu(sig @ W1 + b1) @ W2 + b2.
//
// R1 DFS 151; R2 BFS 90.5; R3 ballot neutral; R4 81.4; R5 3-kernel 82.1;
// R6 single-kernel chain 73.75 (best); R7 32-block global-sync 87.1 (regress:
// cross-XCD coherence costs; distribution disproven twice). Floor ~50us
// (268MB d_ws poison fill + resets). R8 = R6 minus fat: 8 waves (cheaper
// barriers), level-0 expanded straight from registers with a 4-way batched
// chain walker (no L0 frontier, -2 barriers), wave-0-only tail for small
// levels (-3 barriers, no cross-wave sync), MLP bit-identical to R6.

typedef unsigned long long u64;

constexpr int E_EDGES  = 2048;
constexpr int L_WALK   = 8;
constexpr int G_GRAPHS = 128;
constexpr int HID      = 128;
constexpr int N_NODES  = 4096;
constexpr int TPB      = 512;
constexpr int CAP      = 2048;
constexpr int NIL      = 0xFFF;

__device__ __forceinline__ void ballot_push(u64 e2, int lane, int* ctr, u64* buf) {
    u64 m = __ballot(1);
    int leader = __ffsll(m) - 1;
    int rank   = __popcll(m & ((1ull << lane) - 1ull));
    int bpos = 0;
    if (lane == leader) bpos = atomicAdd(ctr, (int)__popcll(m));
    bpos = __shfl(bpos, leader);
    if (bpos + rank < CAP) buf[bpos + rank] = e2;
}

__launch_bounds__(TPB, 1)
__global__ void nbc_all(const int* __restrict__ edge_index,
                        const int* __restrict__ edge_graph,
                        const float* __restrict__ W1,
                        const float* __restrict__ b1,
                        const float* __restrict__ W2,
                        const float* __restrict__ b2,
                        float* __restrict__ out)
{
    // node entry q: src(0:12) | dst(12:24) | hs=head[src](24:36) | next(36:48)
    // frontier  e: s(0:11) | dst_cur(11:23) | ptr(23:35) | g(35:42)
    __shared__ u64 s_bufA[CAP];              // 16 KB; aliased as head[4096] ints
    __shared__ u64 s_bufB[CAP];              // 16 KB
    __shared__ u64 s_node[E_EDGES];          // 16 KB; aliased as s_part later
    __shared__ int s_sig[G_GRAPHS * L_WALK]; // 4 KB
    __shared__ int s_nn[L_WALK + 1];
    __shared__ float s_W1[L_WALK * HID];     // 4 KB
    __shared__ float s_b1[HID];
    __shared__ float s_W2[HID];
    __shared__ float s_b2;

    int* s_head = (int*)s_bufA;              // 4096 ints == 2048 u64 exact alias

    const int t    = threadIdx.x;
    const int lane = t & 63;
    const int wave = t >> 6;

    // ---- phase 1: issue all global loads; init LDS ----
    const int4 se4 = ((const int4*)edge_index)[t];              // src of 4t..4t+3
    const int4 de4 = ((const int4*)(edge_index + E_EDGES))[t];  // dst
    const int4 ge4 = ((const int4*)edge_graph)[t];              // graph ids
    s_W1[t] = W1[t]; s_W1[t + TPB] = W1[t + TPB];
    if (t < HID) { s_b1[t] = b1[t]; s_W2[t] = W2[t]; }
    if (t == 0) s_b2 = b2[0];
    s_sig[t] = 0; s_sig[t + TPB] = 0;
    if (t <= L_WALK) s_nn[t] = 0;
    #pragma unroll
    for (int i = 0; i < 8; ++i) s_head[t + TPB * i] = -1;
    __syncthreads();                                            // B1

    int sev[4], dev[4], gev[4], prevv[4], hsv[4];
    *(int4*)sev = se4; *(int4*)dev = de4; *(int4*)gev = ge4;

    // ---- phase 2: chain build: head[x] = list of edges b with dst_b == x ----
    #pragma unroll
    for (int i = 0; i < 4; ++i)
        prevv[i] = atomicExch(&s_head[dev[i]], 4 * t + i);
    __syncthreads();                                            // B2

    // ---- phase 3: read hs = head[src_e]; write node entries ----
    #pragma unroll
    for (int i = 0; i < 4; ++i) hsv[i] = s_head[sev[i]] & NIL;
    #pragma unroll
    for (int i = 0; i < 4; ++i)
        s_node[4 * t + i] = (u64)sev[i] | ((u64)dev[i] << 12)
                          | ((u64)hsv[i] << 24)
                          | ((u64)(prevv[i] & NIL) << 36);
    __syncthreads();                                            // B3 (head reads done; bufA free)

    // ---- level 0 from registers: 4-way batched chain walk per thread ----
    {
        int ptr4[4];
        #pragma unroll
        for (int i = 0; i < 4; ++i) ptr4[i] = hsv[i];
        while ((ptr4[0] != NIL) | (ptr4[1] != NIL) | (ptr4[2] != NIL) | (ptr4[3] != NIL)) {
            u64 q[4];
            #pragma unroll
            for (int i = 0; i < 4; ++i)
                q[i] = (ptr4[i] != NIL) ? s_node[ptr4[i]] : 0;  // 4 independent ds_reads
            #pragma unroll
            for (int i = 0; i < 4; ++i) {
                if (ptr4[i] != NIL) {
                    int sb = (int)(q[i] & NIL);
                    if (sb != dev[i]) {                          // non-backtracking
                        if (ptr4[i] == 4 * t + i)
                            atomicAdd(&s_sig[gev[i] * L_WALK + 0], 1);
                        u64 e2 = (u64)(4 * t + i)
                               | (((q[i] >> 12) & 0xFFFFFFull) << 11)
                               | ((u64)gev[i] << 35);
                        ballot_push(e2, lane, &s_nn[1], s_bufA);
                    }
                    ptr4[i] = (int)((q[i] >> 36) & NIL);
                }
            }
        }
    }
    __syncthreads();                                            // B4

    // ---- levels 1..7: all-wave until frontier <= 64, then wave-0 tail ----
    u64* cur = s_bufA;
    u64* nxt = s_bufB;
    int d = 1;
    for (; d < L_WALK; ++d) {
        int n_cur = s_nn[d];
        if (n_cur <= 64) break;                                 // tail takes over
        if (n_cur > CAP) n_cur = CAP;
        for (int idx = t; idx < n_cur; idx += TPB) {
            u64 e = cur[idx];
            int s   = (int)( e        & 0x7FF);
            int dcc = (int)((e >> 11) & NIL);
            int ptr = (int)((e >> 23) & NIL);
            u64 gb  = e & (0x7Full << 35);
            while (ptr != NIL) {
                u64 q = s_node[ptr];
                int sb = (int)(q & NIL);
                int nx = (int)((q >> 36) & NIL);
                if (sb != dcc) {
                    if (ptr == s)
                        atomicAdd(&s_sig[(int)(gb >> 35) * L_WALK + d], 1);
                    if (d < L_WALK - 1) {
                        u64 e2 = (u64)s | (((q >> 12) & 0xFFFFFFull) << 11) | gb;
                        ballot_push(e2, lane, &s_nn[d + 1], nxt);
                    }
                }
                ptr = nx;
            }
        }
        u64* tmp = cur; cur = nxt; nxt = tmp;
        __syncthreads();
    }

    if (d < L_WALK && wave == 0) {
        // wave-0-only tail: no barriers; same-wave program order + LDS atomics
        volatile u64* vcur = cur;
        volatile u64* vnxt = nxt;
        for (; d < L_WALK; ++d) {
            int n_cur = s_nn[d];
            if (n_cur > CAP) n_cur = CAP;
            for (int idx = lane; idx < n_cur; idx += 64) {
                u64 e = vcur[idx];
                int s   = (int)( e        & 0x7FF);
                int dcc = (int)((e >> 11) & NIL);
                int ptr = (int)((e >> 23) & NIL);
                u64 gb  = e & (0x7Full << 35);
                while (ptr != NIL) {
                    u64 q = s_node[ptr];
                    int sb = (int)(q & NIL);
                    int nx = (int)((q >> 36) & NIL);
                    if (sb != dcc) {
                        if (ptr == s)
                            atomicAdd(&s_sig[(int)(gb >> 35) * L_WALK + d], 1);
                        if (d < L_WALK - 1) {
                            u64 e2 = (u64)s | (((q >> 12) & 0xFFFFFFull) << 11) | gb;
                            u64 m = __ballot(1);
                            int leader = __ffsll(m) - 1;
                            int rank   = __popcll(m & ((1ull << lane) - 1ull));
                            int bpos = 0;
                            if (lane == leader) bpos = atomicAdd(&s_nn[d + 1], (int)__popcll(m));
                            bpos = __shfl(bpos, leader);
                            if (bpos + rank < CAP) vnxt[bpos + rank] = e2;
                        }
                    }
                    ptr = nx;
                }
            }
            volatile u64* tmp = vcur; vcur = vnxt; vnxt = tmp;
        }
    }
    __syncthreads();                                            // pre-MLP

    // ---- MLP: arithmetic bit-identical to R6 (8 sub-chunks of 16 cols) ----
    float* s_part = (float*)s_node;                             // s_node dead
    for (int slot = t; slot < G_GRAPHS * 8; slot += TPB) {
        const int g   = slot >> 3;
        const int sub = slot & 7;
        float sv[L_WALK];
        #pragma unroll
        for (int k = 0; k < L_WALK; ++k) sv[k] = (float)s_sig[g * L_WALK + k];
        float o = 0.0f;
        const int j0 = sub * 16;
        #pragma unroll 4
        for (int jj = 0; jj < 16; ++jj) {
            int j = j0 + jj;
            float a = s_b1[j];
            #pragma unroll
            for (int k = 0; k < L_WALK; ++k) a += sv[k] * s_W1[k * HID + j];
            o += fmaxf(a, 0.0f) * s_W2[j];
        }
        s_part[slot] = o;
    }
    __syncthreads();
    if (t < G_GRAPHS) {
        float r = s_b2;
        #pragma unroll
        for (int s = 0; s < 8; ++s) r += s_part[t * 8 + s];
        out[t] = r;
    }
}

extern "C" void kernel_launch(void* const* d_in, const int* in_sizes, int n_in,
                              void* d_out, int out_size, void* d_ws, size_t ws_size,
                              hipStream_t stream) {
    const int*   edge_index = (const int*)d_in[0];
    const int*   edge_graph = (const int*)d_in[1];
    const float* W1 = (const float*)d_in[2];
    const float* b1 = (const float*)d_in[3];
    const float* W2 = (const float*)d_in[4];
    const float* b2 = (const float*)d_in[5];
    float* out = (float*)d_out;

    nbc_all<<<1, TPB, 0, stream>>>(edge_index, edge_graph, W1, b1, W2, b2, out);
}

// Round 9
// 73.202 us; speedup vs baseline: 1.1905x; 1.0447x over previous
//
#include <hip/hip_runtime.h>

// NBCModel: non-backtracking closed-walk signature + MLP.
// B[i,j] = (dst_j == src_i) && (src_j != dst_i).  sig[g,k] = sum over edges i
// in graph g of diag(B^{k+1})_i.  out[g] = relu(sig @ W1 + b1) @ W2 + b2.
//
// History: R1 DFS 151; R2 BFS 90.5; R3 ballot neutral; R4 81.4; R5 3-kernel
// 82.1; R6 single-kernel chain-build, 1024thr 73.75 (BEST); R7 32-block
// device-sync 87.1 (cross-XCD coherence cost); R8 512thr fewer-barriers 76.5
// (waves>barriers). Floor ~50us = 39.4us HBM-bound d_ws poison fill + resets.
// R9 = R6 + register-expanded level 0 (no L0 frontier round-trip, single
// s_node write), keeping 16 waves and the R6 MLP bit-identical.

typedef unsigned long long u64;

constexpr int E_EDGES  = 2048;
constexpr int L_WALK   = 8;
constexpr int G_GRAPHS = 128;
constexpr int HID      = 128;
constexpr int N_NODES  = 4096;
constexpr int TPB      = 1024;
constexpr int CAP      = 2048;
constexpr int NIL      = 0xFFF;

__device__ __forceinline__ void ballot_push(u64 e2, int lane, int* ctr, u64* buf) {
    u64 m = __ballot(1);
    int leader = __ffsll(m) - 1;
    int rank   = __popcll(m & ((1ull << lane) - 1ull));
    int bpos = 0;
    if (lane == leader) bpos = atomicAdd(ctr, (int)__popcll(m));
    bpos = __shfl(bpos, leader);
    if (bpos + rank < CAP) buf[bpos + rank] = e2;
}

__launch_bounds__(TPB, 1)
__global__ void nbc_all(const int* __restrict__ edge_index,
                        const int* __restrict__ edge_graph,
                        const float* __restrict__ W1,
                        const float* __restrict__ b1,
                        const float* __restrict__ W2,
                        const float* __restrict__ b2,
                        float* __restrict__ out)
{
    // node entry q: src(0:12) | dst(12:24) | hs=head[src](24:36) | next(36:48)
    // frontier  e: s(0:11) | dst_cur(11:23) | ptr(23:35) | g(35:42)
    __shared__ u64 s_bufA[CAP];              // 16 KB; aliased as head[4096] ints
    __shared__ u64 s_bufB[CAP];              // 16 KB
    __shared__ u64 s_node[E_EDGES];          // 16 KB; aliased as s_part later
    __shared__ int s_sig[G_GRAPHS * L_WALK]; // 4 KB
    __shared__ int s_nn[L_WALK + 1];
    __shared__ float s_W1[L_WALK * HID];     // 4 KB
    __shared__ float s_b1[HID];
    __shared__ float s_W2[HID];
    __shared__ float s_b2;

    int* s_head = (int*)s_bufA;              // 4096 ints == 2048 u64 exact alias

    const int t    = threadIdx.x;
    const int lane = t & 63;

    // ---- phase 1: issue all global loads early; init LDS ----
    const int2 se2 = ((const int2*)edge_index)[t];              // src of 2t,2t+1
    const int2 de2 = ((const int2*)(edge_index + E_EDGES))[t];  // dst
    const int2 ge2 = ((const int2*)edge_graph)[t];              // graph ids
    s_W1[t] = W1[t];                         // L_WALK*HID == 1024
    if (t < HID) { s_b1[t] = b1[t]; s_W2[t] = W2[t]; }
    if (t == 0) s_b2 = b2[0];
    s_sig[t] = 0;                            // G*L == 1024
    if (t <= L_WALK) s_nn[t] = 0;
    s_head[t] = -1; s_head[t + TPB] = -1;
    s_head[t + 2 * TPB] = -1; s_head[t + 3 * TPB] = -1;
    __syncthreads();                                            // B1

    // ---- phase 2: chain build: head[x] = list of edges b with dst_b == x ----
    const int e0 = 2 * t, e1 = 2 * t + 1;
    const int prev0 = atomicExch(&s_head[de2.x], e0);
    const int prev1 = atomicExch(&s_head[de2.y], e1);
    __syncthreads();                                            // B2

    // ---- phase 3: read hs = head[src_e]; single full node write ----
    const int h0 = s_head[se2.x] & NIL;
    const int h1 = s_head[se2.y] & NIL;
    s_node[e0] = (u64)se2.x | ((u64)de2.x << 12) | ((u64)h0 << 24)
               | ((u64)(prev0 & NIL) << 36);
    s_node[e1] = (u64)se2.y | ((u64)de2.y << 12) | ((u64)h1 << 24)
               | ((u64)(prev1 & NIL) << 36);
    __syncthreads();                                            // B3 (heads read; bufA free)

    // ---- level 0 from registers: 2-way interleaved chain chase ----
    {
        int p0 = h0, p1 = h1;
        while ((p0 != NIL) | (p1 != NIL)) {
            u64 q0 = (p0 != NIL) ? s_node[p0] : 0;   // independent ds_reads
            u64 q1 = (p1 != NIL) ? s_node[p1] : 0;
            if (p0 != NIL) {
                int sb = (int)(q0 & NIL);
                if (sb != de2.x) {                    // non-backtracking
                    if (p0 == e0) atomicAdd(&s_sig[ge2.x * L_WALK + 0], 1);
                    u64 en = (u64)e0 | (((q0 >> 12) & 0xFFFFFFull) << 11)
                           | ((u64)ge2.x << 35);
                    ballot_push(en, lane, &s_nn[1], s_bufA);
                }
                p0 = (int)((q0 >> 36) & NIL);
            }
            if (p1 != NIL) {
                int sb = (int)(q1 & NIL);
                if (sb != de2.y) {
                    if (p1 == e1) atomicAdd(&s_sig[ge2.y * L_WALK + 0], 1);
                    u64 en = (u64)e1 | (((q1 >> 12) & 0xFFFFFFull) << 11)
                           | ((u64)ge2.y << 35);
                    ballot_push(en, lane, &s_nn[1], s_bufA);
                }
                p1 = (int)((q1 >> 36) & NIL);
            }
        }
    }
    __syncthreads();                                            // B4

    // ---- levels 1..7: identical to R6 ----
    u64* cur = s_bufA;
    u64* nxt = s_bufB;
    for (int d = 1; d < L_WALK; ++d) {
        int n_cur = s_nn[d];
        if (n_cur > CAP) n_cur = CAP;
        for (int idx = t; idx < n_cur; idx += TPB) {
            u64 e = cur[idx];
            int s   = (int)( e        & 0x7FF);
            int dcc = (int)((e >> 11) & NIL);
            int ptr = (int)((e >> 23) & NIL);
            u64 gb  = e & (0x7Full << 35);
            while (ptr != NIL) {
                u64 q = s_node[ptr];
                int sb = (int)(q & NIL);
                int nx = (int)((q >> 36) & NIL);
                if (sb != dcc) {
                    if (ptr == s)
                        atomicAdd(&s_sig[(int)(gb >> 35) * L_WALK + d], 1);
                    if (d < L_WALK - 1) {
                        u64 e2 = (u64)s | (((q >> 12) & 0xFFFFFFull) << 11) | gb;
                        ballot_push(e2, lane, &s_nn[d + 1], nxt);
                    }
                }
                ptr = nx;
            }
        }
        u64* tmp = cur; cur = nxt; nxt = tmp;
        __syncthreads();
    }

    // ---- MLP: bit-identical to R6 ----
    float* s_part = (float*)s_node;                             // s_node dead
    {
        const int g   = t >> 3;
        const int sub = t & 7;
        float sv[L_WALK];
        #pragma unroll
        for (int k = 0; k < L_WALK; ++k) sv[k] = (float)s_sig[g * L_WALK + k];
        float o = 0.0f;
        const int j0 = sub * 16;
        #pragma unroll 4
        for (int jj = 0; jj < 16; ++jj) {
            int j = j0 + jj;
            float a = s_b1[j];
            #pragma unroll
            for (int k = 0; k < L_WALK; ++k) a += sv[k] * s_W1[k * HID + j];
            o += fmaxf(a, 0.0f) * s_W2[j];
        }
        s_part[t] = o;
    }
    __syncthreads();
    if (t < G_GRAPHS) {
        float r = s_b2;
        #pragma unroll
        for (int s = 0; s < 8; ++s) r += s_part[t * 8 + s];
        out[t] = r;
    }
}

extern "C" void kernel_launch(void* const* d_in, const int* in_sizes, int n_in,
                              void* d_out, int out_size, void* d_ws, size_t ws_size,
                              hipStream_t stream) {
    const int*   edge_index = (const int*)d_in[0];
    const int*   edge_graph = (const int*)d_in[1];
    const float* W1 = (const float*)d_in[2];
    const float* b1 = (const float*)d_in[3];
    const float* W2 = (const float*)d_in[4];
    const float* b2 = (const float*)d_in[5];
    float* out = (float*)d_out;

    nbc_all<<<1, TPB, 0, stream>>>(edge_index, edge_graph, W1, b1, W2, b2, out);
}